// Round 1
// baseline (2548.752 us; speedup 1.0000x reference)
//
#include <hip/hip_runtime.h>
#include <stdint.h>

#define T_SEQ 2048

typedef __attribute__((ext_vector_type(8))) short short8;
typedef __attribute__((ext_vector_type(4))) float f32x4;

__device__ __forceinline__ unsigned short f2bf(float f){
  unsigned int u = __float_as_uint(f);
  unsigned int r = u + 0x7fffu + ((u >> 16) & 1u);
  return (unsigned short)(r >> 16);
}
__device__ __forceinline__ float bf2f(unsigned short h){
  return __uint_as_float(((unsigned int)h) << 16);
}
__device__ __forceinline__ float sig_(float x){
  float e = __builtin_amdgcn_exp2f(-1.44269504089f * x);
  return __builtin_amdgcn_rcpf(1.0f + e);
}
__device__ __forceinline__ float tanh_(float x){
  float e = __builtin_amdgcn_exp2f(2.88539008178f * x);
  return 1.0f - 2.0f * __builtin_amdgcn_rcpf(1.0f + e);
}
// Hamilton block value W[qr*64+kr][qc*192+nc]; comp = qr^qc, sign mask 0x5390
__device__ __forceinline__ float ham_val(int qr, int qc, int kr, int nc,
    const float* wr, const float* wi, const float* wj, const float* wk){
  int cc = qr ^ qc;
  const float* w = (cc==0)?wr:(cc==1)?wi:(cc==2)?wj:wk;
  float v = w[kr*192 + nc];
  if ((0x5390u >> (qr*4+qc)) & 1u) v = -v;
  return v;
}

// Build B'^T for the input GEMM: BT[c][k'], c = permuted column, k' in [0,768):
// k'<256 -> hi(W_ih), k' in [256,512) -> lo(W_ih), k'>=512 -> hi(W_ih)
__global__ __launch_bounds__(256) void k_prep_bt(const float* __restrict__ wr,
    const float* __restrict__ wi, const float* __restrict__ wj,
    const float* __restrict__ wk, unsigned short* __restrict__ BT){
  int idx = blockIdx.x*256 + threadIdx.x;       // 768*768
  int c = idx / 768, kp = idx - c*768;
  int kk = kp & 255, piece = kp >> 8;
  int qr = kk >> 6, kr = kk & 63;
  int e = (c/48)*16 + (c & 15);
  int g = (c % 48) >> 4;
  int qc = e >> 6;
  int nc = g*64 + (e & 63);
  float v = ham_val(qr, qc, kr, nc, wr, wi, wj, wk);
  unsigned short hi = f2bf(v);
  unsigned short o = (piece == 1) ? f2bf(v - bf2f(hi)) : hi;
  BT[(size_t)c*768 + kp] = o;
}

// Component-packed W_hh B-fragments of the 4 RAW base matrices (no Hamilton
// signs, no block expansion). Layout: [(wv*3+s)*4 + m][lane] -> short8.
// Wave wv owns kt = wv>>2, tiles (wv&3)*3 + s (s=0..2), all 4 matrices m.
__global__ __launch_bounds__(256) void k_prep_whh(const float* __restrict__ wr,
    const float* __restrict__ wi, const float* __restrict__ wj,
    const float* __restrict__ wk, unsigned short* __restrict__ WF){
  int idx = blockIdx.x*256 + threadIdx.x;       // 24 blocks -> 6144 entries
  int lane = idx & 63;
  int m = (idx >> 6) & 3;
  int us = idx >> 8;                            // wv*3+s, 0..23
  int wv = us / 3, s = us - wv*3;
  int ktw = wv >> 2;
  int tile = (wv & 3)*3 + s;
  int quad = lane >> 4, u = lane & 15;
  int col = tile*16 + u;                        // 0..191 (gate*64+idx)
  const float* w = (m==0)?wr:(m==1)?wi:(m==2)?wj:wk;
  short8 o;
  #pragma unroll
  for (int j = 0; j < 8; j++){
    int k = ktw*32 + quad*8 + j;                // 0..63 (H rows)
    o[j] = (short)f2bf(w[k*192 + col]);
  }
  *(short8*)(WF + (size_t)idx*8) = o;
}

__global__ __launch_bounds__(256) void k_prep_bias(const float* __restrict__ bih,
    const float* __restrict__ bhh, float* __restrict__ bias){
  int c = blockIdx.x*256 + threadIdx.x;         // 768
  int e = (c/48)*16 + (c & 15);
  int g = (c % 48) >> 4;
  int n = (e >> 6)*192 + g*64 + (e & 63);
  bias[c] = bih[n] + bhh[n];
}

// gi = [x_hi x_hi x_lo] @ [W_hi; W_lo; W_hi] + (b_ih+b_hh), columns permuted.
// 128x128 tile, BK=64, 12 K-chunks. XOR-swizzled LDS (chunk ^= row&7).
__global__ __launch_bounds__(256) void k_gemm_gi(const float* __restrict__ x,
    const unsigned short* __restrict__ BT, const float* __restrict__ bias,
    float* __restrict__ gi){
  __shared__ unsigned short As[128*64];
  __shared__ unsigned short Bs[128*64];
  int tid = threadIdx.x;
  int mb = blockIdx.x / 6, nb = blockIdx.x - mb*6;   // nb fastest: A-slab L2 reuse
  int lane = tid & 63, wid = tid >> 6;
  int quad = lane >> 4, u = lane & 15;
  int wvm = wid >> 1, wvn = wid & 1;
  int srow = tid >> 3, cb = tid & 7;
  f32x4 acc[4][4] = {};
  for (int kc = 0; kc < 12; kc++){
    bool lop = (kc >= 8);
    int kbase = (kc & 3) * 64;
    #pragma unroll
    for (int rd = 0; rd < 4; rd++){
      int m = rd*32 + srow;
      int lc = cb ^ (m & 7);
      const float* xp = x + (size_t)(mb*128 + m)*256 + kbase + lc*8;
      float4 v0 = *(const float4*)xp;
      float4 v1 = *(const float4*)(xp + 4);
      float vv[8] = {v0.x, v0.y, v0.z, v0.w, v1.x, v1.y, v1.z, v1.w};
      short8 ov;
      #pragma unroll
      for (int q = 0; q < 8; q++){
        unsigned short hi = f2bf(vv[q]);
        ov[q] = (short)(lop ? f2bf(vv[q] - bf2f(hi)) : hi);
      }
      *(short8*)&As[m*64 + cb*8] = ov;
    }
    #pragma unroll
    for (int rd = 0; rd < 4; rd++){
      int c = rd*32 + srow;
      int lc = cb ^ (c & 7);
      const unsigned short* bp = BT + (size_t)(nb*128 + c)*768 + kc*64 + lc*8;
      *(short8*)&Bs[c*64 + cb*8] = *(const short8*)bp;
    }
    __syncthreads();
    #pragma unroll
    for (int ks = 0; ks < 2; ks++){
      short8 af[4], bf[4];
      #pragma unroll
      for (int i=0;i<4;i++){
        int row = 64*wvm + 16*i + u;
        af[i] = *(const short8*)&As[row*64 + ((4*ks+quad) ^ (u & 7))*8];
      }
      #pragma unroll
      for (int j=0;j<4;j++){
        int row = 64*wvn + 16*j + u;
        bf[j] = *(const short8*)&Bs[row*64 + ((4*ks+quad) ^ (u & 7))*8];
      }
      #pragma unroll
      for (int i=0;i<4;i++)
        #pragma unroll
        for (int j=0;j<4;j++)
          acc[i][j] = __builtin_amdgcn_mfma_f32_16x16x32_bf16(af[i], bf[j], acc[i][j], 0, 0, 0);
    }
    __syncthreads();
  }
  int cb2 = nb*128 + 64*wvn;
  #pragma unroll
  for (int j=0;j<4;j++){
    float bj = bias[cb2 + 16*j + u];
    #pragma unroll
    for (int i=0;i<4;i++){
      float* gp = gi + (size_t)(mb*128 + 64*wvm + 16*i + quad*4)*768 + cb2 + 16*j + u;
      #pragma unroll
      for (int r=0;r<4;r++)
        gp[(size_t)r*768] = acc[i][j][r] + bj;
    }
  }
}

// Recurrence: 1 workgroup = 1 batch chain, 8 waves. Component-packed MFMA:
// A rows 0..3 = h_r,h_i,h_j,h_k (rows repeat mod 4), B = raw W_m (m=r,i,j,k).
// One MFMA yields h_qr@W_m for all 4 qr in D rows; lanes combine with Hamilton
// signs (o_qc = sum_r +/- A[m=r^qc][r]) locally. 96 MFMA/step (was 384).
// Partial sums (kt=0/1 wave halves) exchanged via padded LDS; 2 barriers/step.
__global__ __launch_bounds__(512, 2) void k_rec(const float* __restrict__ gi,
    const short8* __restrict__ WF, const float* __restrict__ hx,
    float* __restrict__ out){
  __shared__ unsigned short hbuf[2][256];
  __shared__ float opart[1600];                 // [kt*4+qc][200] (stride 200: 2-way banks only)
  int tid = threadIdx.x;
  int b = blockIdx.x;
  int lane = tid & 63, wv = tid >> 6;
  int quad = lane >> 4, u = lane & 15;
  int p16 = quad & 1;
  int ktw = wv >> 2;                            // this wave's K-half
  short8 Bf[3][4];                              // 3 tiles x 4 base matrices
  #pragma unroll
  for (int s = 0; s < 3; s++)
    #pragma unroll
    for (int m = 0; m < 4; m++)
      Bf[s][m] = WF[(size_t)(((wv*3 + s)*4 + m)*64 + lane)];
  // A-fragment: row = lane&15 -> comp = u&3 (4x replicated), k = ktw*32+quad*8+j
  int aoff = (u & 3)*64 + ktw*32 + quad*8;
  int e = wv*32 + (lane & 31);
  float h = hx[b*256 + e];
  if (lane < 32) hbuf[0][e] = f2bf(h);
  int q = wv >> 1;                              // component of this wave's h-elements
  int idxq = (wv & 1)*32 + p16*16 + u;          // index within component
  int ro0 = q*200 + idxq;                       // opart read base (kt0); +800 for kt1
  int wo[3];
  #pragma unroll
  for (int s = 0; s < 3; s++){
    int tile = (wv & 3)*3 + s;
    wo[s] = (ktw*4 + quad)*200 + tile*16 + u;   // qc = quad
  }
  int c0 = wv*96 + p16*48 + u;
  const float* gbase = gi + (size_t)b*768 + c0;
  float gc0 = gbase[0], gc1 = gbase[16], gc2 = gbase[32];
  const float* g1p = gbase + (size_t)49152;     // gi[t=1]
  float p0 = g1p[0], p1 = g1p[16], p2 = g1p[32];
  float* outp = out + (size_t)b*256 + e;
  __syncthreads();
  for (int t = 0; t < T_SEQ; t++){
    int t2 = (t+2 < T_SEQ) ? (t+2) : (T_SEQ-1);
    const float* gn = gbase + (size_t)t2 * 49152;
    float n0 = gn[0], n1 = gn[16], n2 = gn[32]; // depth-2 gi prefetch
    const unsigned short* hb = hbuf[t & 1];
    short8 a = *(const short8*)&hb[aoff];       // broadcast-friendly b128
    f32x4 A[3][4];
    #pragma unroll
    for (int s = 0; s < 3; s++)
      #pragma unroll
      for (int m = 0; m < 4; m++)
        A[s][m] = __builtin_amdgcn_mfma_f32_16x16x32_bf16(a, Bf[s][m],
                    (f32x4){0.f, 0.f, 0.f, 0.f}, 0, 0, 0);
    #pragma unroll
    for (int s = 0; s < 3; s++){
      float o;
      if      (quad == 0) o = A[s][0][0] - A[s][1][1] - A[s][2][2] - A[s][3][3];
      else if (quad == 1) o = A[s][1][0] + A[s][0][1] - A[s][3][2] + A[s][2][3];
      else if (quad == 2) o = A[s][2][0] + A[s][3][1] + A[s][0][2] - A[s][1][3];
      else                o = A[s][3][0] - A[s][2][1] + A[s][1][2] + A[s][0][3];
      opart[wo[s]] = o;
    }
    __syncthreads();                            // opart writes -> reads
    float pre0 = opart[ro0      ] + opart[800 + ro0      ];
    float pre1 = opart[ro0 +  64] + opart[800 + ro0 +  64];
    float pre2 = opart[ro0 + 128] + opart[800 + ro0 + 128];
    float r = sig_(gc0 + pre0);
    float z = sig_(gc1 + pre1);
    float nn = tanh_(gc2 + r * pre2);
    h = nn + z * (h - nn);
    if (lane < 32){
      outp[(size_t)t * (64*256)] = h;
      hbuf[(t+1) & 1][e] = f2bf(h);
    }
    gc0 = p0; gc1 = p1; gc2 = p2;
    p0 = n0; p1 = n1; p2 = n2;
    __syncthreads();                            // hbuf writes -> next reads; opart reads -> next writes
  }
  if (lane < 32) out[(size_t)T_SEQ*64*256 + b*256 + e] = h;
}

extern "C" void kernel_launch(void* const* d_in, const int* in_sizes, int n_in,
                              void* d_out, int out_size, void* d_ws, size_t ws_size,
                              hipStream_t stream){
  const float* x    = (const float*)d_in[0];
  const float* hx   = (const float*)d_in[1];
  const float* wihr = (const float*)d_in[2];
  const float* wihi = (const float*)d_in[3];
  const float* wihj = (const float*)d_in[4];
  const float* wihk = (const float*)d_in[5];
  const float* whhr = (const float*)d_in[6];
  const float* whhi = (const float*)d_in[7];
  const float* whhj = (const float*)d_in[8];
  const float* whhk = (const float*)d_in[9];
  const float* bih  = (const float*)d_in[10];
  const float* bhh  = (const float*)d_in[11];
  char* ws = (char*)d_ws;
  float* gi          = (float*)ws;                            // 402,653,184 B
  unsigned short* BT = (unsigned short*)(ws + 402653184ull);  //   1,179,648 B
  unsigned short* WF = (unsigned short*)(ws + 403832832ull);  //      98,304 B
  float* bias        = (float*)(ws + 404226048ull);           //       3,072 B
  k_prep_bt  <<<dim3(2304), dim3(256), 0, stream>>>(wihr, wihi, wihj, wihk, BT);
  k_prep_whh <<<dim3(24),   dim3(256), 0, stream>>>(whhr, whhi, whhj, whhk, WF);
  k_prep_bias<<<dim3(3),    dim3(256), 0, stream>>>(bih, bhh, bias);
  k_gemm_gi  <<<dim3(6144), dim3(256), 0, stream>>>(x, BT, bias, gi);
  k_rec      <<<dim3(64),   dim3(512), 0, stream>>>(gi, (const short8*)WF, hx, (float*)d_out);
}

// Round 4
// 1460.813 us; speedup vs baseline: 1.7447x; 1.7447x over previous
//
#include <hip/hip_runtime.h>
#include <stdint.h>

#define T_SEQ 2048

typedef __attribute__((ext_vector_type(8))) short short8;
typedef __attribute__((ext_vector_type(4))) float f32x4;

__device__ __forceinline__ unsigned short f2bf(float f){
  unsigned int u = __float_as_uint(f);
  unsigned int r = u + 0x7fffu + ((u >> 16) & 1u);
  return (unsigned short)(r >> 16);
}
__device__ __forceinline__ float bf2f(unsigned short h){
  return __uint_as_float(((unsigned int)h) << 16);
}
__device__ __forceinline__ float sig_(float x){
  float e = __builtin_amdgcn_exp2f(-1.44269504089f * x);
  return __builtin_amdgcn_rcpf(1.0f + e);
}
__device__ __forceinline__ float tanh_(float x){
  float e = __builtin_amdgcn_exp2f(2.88539008178f * x);
  return 1.0f - 2.0f * __builtin_amdgcn_rcpf(1.0f + e);
}
// Hamilton block value W[qr*64+kr][qc*192+nc]; comp = qr^qc, sign mask 0x5390
__device__ __forceinline__ float ham_val(int qr, int qc, int kr, int nc,
    const float* wr, const float* wi, const float* wj, const float* wk){
  int cc = qr ^ qc;
  const float* w = (cc==0)?wr:(cc==1)?wi:(cc==2)?wj:wk;
  float v = w[kr*192 + nc];
  if ((0x5390u >> (qr*4+qc)) & 1u) v = -v;
  return v;
}

// Build B'^T for the input GEMM: BT[c][k'], c = permuted column, k' in [0,768):
// k'<256 -> hi(W_ih), k' in [256,512) -> lo(W_ih), k'>=512 -> hi(W_ih)
__global__ __launch_bounds__(256) void k_prep_bt(const float* __restrict__ wr,
    const float* __restrict__ wi, const float* __restrict__ wj,
    const float* __restrict__ wk, unsigned short* __restrict__ BT){
  int idx = blockIdx.x*256 + threadIdx.x;       // 768*768
  int c = idx / 768, kp = idx - c*768;
  int kk = kp & 255, piece = kp >> 8;
  int qr = kk >> 6, kr = kk & 63;
  int e = (c/48)*16 + (c & 15);
  int g = (c % 48) >> 4;
  int qc = e >> 6;
  int nc = g*64 + (e & 63);
  float v = ham_val(qr, qc, kr, nc, wr, wi, wj, wk);
  unsigned short hi = f2bf(v);
  unsigned short o = (piece == 1) ? f2bf(v - bf2f(hi)) : hi;
  BT[(size_t)c*768 + kp] = o;
}

// Component-packed W_hh B-fragments of the 4 RAW base matrices.
// Layout: idx = ((w*3+s)*4 + m)*2 + kt (x64 lanes); wave w owns cols
// s*64 + w*16 + u; kt = K-half (chained in-wave in k_rec).
__global__ __launch_bounds__(256) void k_prep_whh(const float* __restrict__ wr,
    const float* __restrict__ wi, const float* __restrict__ wj,
    const float* __restrict__ wk, unsigned short* __restrict__ WF){
  int idx = blockIdx.x*256 + threadIdx.x;       // 24 blocks -> 6144 entries
  int lane = idx & 63;
  int kt = (idx >> 6) & 1;
  int m  = (idx >> 7) & 3;
  int ws3 = idx >> 9;                           // w*3+s, 0..11
  int w = ws3 / 3, s = ws3 - w*3;
  int quad = lane >> 4, u = lane & 15;
  int col = s*64 + w*16 + u;                    // 0..191 (gate*64 + n)
  const float* mat = (m==0)?wr:(m==1)?wi:(m==2)?wj:wk;
  short8 o;
  #pragma unroll
  for (int j = 0; j < 8; j++){
    int k = kt*32 + quad*8 + j;                 // 0..63 (H rows)
    o[j] = (short)f2bf(mat[k*192 + col]);
  }
  *(short8*)(WF + (size_t)idx*8) = o;
}

__global__ __launch_bounds__(256) void k_prep_bias(const float* __restrict__ bih,
    const float* __restrict__ bhh, float* __restrict__ bias){
  int c = blockIdx.x*256 + threadIdx.x;         // 768
  int e = (c/48)*16 + (c & 15);
  int g = (c % 48) >> 4;
  int n = (e >> 6)*192 + g*64 + (e & 63);
  bias[c] = bih[n] + bhh[n];
}

// gi = [x_hi x_hi x_lo] @ [W_hi; W_lo; W_hi] + (b_ih+b_hh), columns permuted.
// 128x128 tile, BK=64, 12 K-chunks. XOR-swizzled LDS (chunk ^= row&7).
__global__ __launch_bounds__(256) void k_gemm_gi(const float* __restrict__ x,
    const unsigned short* __restrict__ BT, const float* __restrict__ bias,
    float* __restrict__ gi){
  __shared__ unsigned short As[128*64];
  __shared__ unsigned short Bs[128*64];
  int tid = threadIdx.x;
  int mb = blockIdx.x / 6, nb = blockIdx.x - mb*6;   // nb fastest: A-slab L2 reuse
  int lane = tid & 63, wid = tid >> 6;
  int quad = lane >> 4, u = lane & 15;
  int wvm = wid >> 1, wvn = wid & 1;
  int srow = tid >> 3, cb = tid & 7;
  f32x4 acc[4][4] = {};
  for (int kc = 0; kc < 12; kc++){
    bool lop = (kc >= 8);
    int kbase = (kc & 3) * 64;
    #pragma unroll
    for (int rd = 0; rd < 4; rd++){
      int m = rd*32 + srow;
      int lc = cb ^ (m & 7);
      const float* xp = x + (size_t)(mb*128 + m)*256 + kbase + lc*8;
      float4 v0 = *(const float4*)xp;
      float4 v1 = *(const float4*)(xp + 4);
      float vv[8] = {v0.x, v0.y, v0.z, v0.w, v1.x, v1.y, v1.z, v1.w};
      short8 ov;
      #pragma unroll
      for (int q = 0; q < 8; q++){
        unsigned short hi = f2bf(vv[q]);
        ov[q] = (short)(lop ? f2bf(vv[q] - bf2f(hi)) : hi);
      }
      *(short8*)&As[m*64 + cb*8] = ov;
    }
    #pragma unroll
    for (int rd = 0; rd < 4; rd++){
      int c = rd*32 + srow;
      int lc = cb ^ (c & 7);
      const unsigned short* bp = BT + (size_t)(nb*128 + c)*768 + kc*64 + lc*8;
      *(short8*)&Bs[c*64 + cb*8] = *(const short8*)bp;
    }
    __syncthreads();
    #pragma unroll
    for (int ks = 0; ks < 2; ks++){
      short8 af[4], bf[4];
      #pragma unroll
      for (int i=0;i<4;i++){
        int row = 64*wvm + 16*i + u;
        af[i] = *(const short8*)&As[row*64 + ((4*ks+quad) ^ (u & 7))*8];
      }
      #pragma unroll
      for (int j=0;j<4;j++){
        int row = 64*wvn + 16*j + u;
        bf[j] = *(const short8*)&Bs[row*64 + ((4*ks+quad) ^ (u & 7))*8];
      }
      #pragma unroll
      for (int i=0;i<4;i++)
        #pragma unroll
        for (int j=0;j<4;j++)
          acc[i][j] = __builtin_amdgcn_mfma_f32_16x16x32_bf16(af[i], bf[j], acc[i][j], 0, 0, 0);
    }
    __syncthreads();
  }
  int cb2 = nb*128 + 64*wvn;
  #pragma unroll
  for (int j=0;j<4;j++){
    float bj = bias[cb2 + 16*j + u];
    #pragma unroll
    for (int i=0;i<4;i++){
      float* gp = gi + (size_t)(mb*128 + 64*wvm + 16*i + quad*4)*768 + cb2 + 16*j + u;
      #pragma unroll
      for (int r=0;r<4;r++)
        gp[(size_t)r*768] = acc[i][j][r] + bj;
    }
  }
}

// Recurrence: 1 WG = 1 batch chain, 4 waves (256 thr), 1 wave/SIMD.
// Wave w owns cols g*64 + w*16 + u for all gates g. K=64 chained in-wave
// (2 MFMAs/acc) -> no cross-wave partial exchange; only h is exchanged
// via LDS with ONE raw barrier/step (no vmcnt(0) drain - gi prefetch loads
// and out stores stay in flight across barriers). Barrier is bracketed by
// memory-clobber asm on BOTH sides: lgkmcnt(0) before (drain ds_write),
// empty clobber after (s_barrier is IntrNoMem - loads would hoist above it).
// A rows use permutation sigma(row)=(row&3)^(row>>2) so the Hamilton
// combine is the acc diagonal with per-lane +-1 signs (no divergence):
//   o_s = acc[4s+0][0] + sg1*acc[4s+1][1] + sg2*acc[4s+2][2] + sg3*acc[4s+3][3]
// sg_r = sign(r^quad, quad) from mask 0x5390.
// gi prefetch: depth-4 rotating register sets (x4 unroll, static indices);
// prefetch address clamped to gi's last row (values past t=2047 never used).
__global__ __launch_bounds__(256, 1) void k_rec(const float* __restrict__ gi,
    const short8* __restrict__ WF, const float* __restrict__ hx,
    float* __restrict__ out){
  __shared__ unsigned short hbuf[2][256];
  int tid = threadIdx.x;
  int b = blockIdx.x;
  int lane = tid & 63, w = tid >> 6;
  int quad = lane >> 4, u = lane & 15;
  short8 Bf[12][2];                             // [s*4+m][kt] : 96 VGPRs
  #pragma unroll
  for (int s = 0; s < 3; s++)
    #pragma unroll
    for (int m = 0; m < 4; m++)
      #pragma unroll
      for (int kt = 0; kt < 2; kt++)
        Bf[s*4+m][kt] = WF[(size_t)((((w*3+s)*4+m)*2+kt)*64 + lane)];
  // A row u holds h_{sigma(u)}, sigma(u) = (u&3)^(u>>2)
  int aoff = (((u & 3) ^ (u >> 2)) * 64) + quad*8;
  float sg1 = (quad & 1)              ?  1.f : -1.f;
  float sg2 = (quad==1 || quad==2)    ?  1.f : -1.f;
  float sg3 = (quad >> 1)             ?  1.f : -1.f;
  int e = quad*64 + w*16 + u;                   // comp*64 + n
  float h = hx[b*256 + e];
  hbuf[0][e] = f2bf(h);
  // gi column for (e, gate g): c = (e>>4)*48 + g*16 + (e&15)
  const float* gl = gi + (size_t)b*768 + (quad*4 + w)*48 + u;
  float* outp = out + (size_t)b*256 + e;
  float pf[4][3];
  #pragma unroll
  for (int j = 0; j < 4; j++){
    const float* p = gl + (size_t)j*49152;
    pf[j][0] = p[0]; pf[j][1] = p[16]; pf[j][2] = p[32];
  }
  const float* gp   = gl + (size_t)4*49152;
  const float* glast = gl + (size_t)(T_SEQ-1)*49152;
  asm volatile("s_waitcnt lgkmcnt(0)" ::: "memory");
  __builtin_amdgcn_s_barrier();
  asm volatile("" ::: "memory");
  for (int t0 = 0; t0 < T_SEQ; t0 += 4){
    #pragma unroll
    for (int j = 0; j < 4; j++){
      const unsigned short* hb = hbuf[j & 1];
      short8 a0 = *(const short8*)&hb[aoff];
      short8 a1 = *(const short8*)&hb[aoff + 32];
      f32x4 acc[12];
      #pragma unroll
      for (int sm = 0; sm < 12; sm++)
        acc[sm] = __builtin_amdgcn_mfma_f32_16x16x32_bf16(a0, Bf[sm][0],
                    (f32x4){0.f,0.f,0.f,0.f}, 0, 0, 0);
      #pragma unroll
      for (int sm = 0; sm < 12; sm++)
        acc[sm] = __builtin_amdgcn_mfma_f32_16x16x32_bf16(a1, Bf[sm][1],
                    acc[sm], 0, 0, 0);
      float o0 = acc[0][0] + sg1*acc[1][1] + sg2*acc[2][2]  + sg3*acc[3][3];
      float o1 = acc[4][0] + sg1*acc[5][1] + sg2*acc[6][2]  + sg3*acc[7][3];
      float o2 = acc[8][0] + sg1*acc[9][1] + sg2*acc[10][2] + sg3*acc[11][3];
      float r  = sig_(pf[j][0] + o0);
      float z  = sig_(pf[j][1] + o1);
      float nn = tanh_(pf[j][2] + r * o2);
      h = nn + z * (h - nn);
      int t = t0 + j;
      outp[(size_t)t * 16384] = h;
      hbuf[(j + 1) & 1][e] = f2bf(h);
      const float* pv = (gp <= glast) ? gp : glast;   // clamp: stay inside gi
      pf[j][0] = pv[0]; pf[j][1] = pv[16]; pf[j][2] = pv[32];  // for t+4
      gp += 49152;
      asm volatile("s_waitcnt lgkmcnt(0)" ::: "memory");
      __builtin_amdgcn_s_barrier();
      asm volatile("" ::: "memory");
    }
  }
  out[(size_t)T_SEQ * 16384 + b*256 + e] = h;
}

extern "C" void kernel_launch(void* const* d_in, const int* in_sizes, int n_in,
                              void* d_out, int out_size, void* d_ws, size_t ws_size,
                              hipStream_t stream){
  const float* x    = (const float*)d_in[0];
  const float* hx   = (const float*)d_in[1];
  const float* wihr = (const float*)d_in[2];
  const float* wihi = (const float*)d_in[3];
  const float* wihj = (const float*)d_in[4];
  const float* wihk = (const float*)d_in[5];
  const float* whhr = (const float*)d_in[6];
  const float* whhi = (const float*)d_in[7];
  const float* whhj = (const float*)d_in[8];
  const float* whhk = (const float*)d_in[9];
  const float* bih  = (const float*)d_in[10];
  const float* bhh  = (const float*)d_in[11];
  char* ws = (char*)d_ws;
  float* gi          = (float*)ws;                            // 402,653,184 B
  unsigned short* BT = (unsigned short*)(ws + 402653184ull);  //   1,179,648 B
  unsigned short* WF = (unsigned short*)(ws + 403832832ull);  //      98,304 B
  float* bias        = (float*)(ws + 404226048ull);           //       3,072 B
  k_prep_bt  <<<dim3(2304), dim3(256), 0, stream>>>(wihr, wihi, wihj, wihk, BT);
  k_prep_whh <<<dim3(24),   dim3(256), 0, stream>>>(whhr, whhi, whhj, whhk, WF);
  k_prep_bias<<<dim3(3),    dim3(256), 0, stream>>>(bih, bhh, bias);
  k_gemm_gi  <<<dim3(6144), dim3(256), 0, stream>>>(x, BT, bias, gi);
  k_rec      <<<dim3(64),   dim3(256), 0, stream>>>(gi, (const short8*)WF, hx, (float*)d_out);
}